// Round 1
// baseline (1602.248 us; speedup 1.0000x reference)
//
#include <hip/hip_runtime.h>
#include <cstdint>
#include <cstddef>

#define THRESH_F 0.5f
#define VAR0_F 0.1f
#define VAR1_F 0.2f
#define NEG_POS_K 3
#define MAXOBJ 64

// ---------------- init ----------------
__global__ void init_kernel(unsigned long long* __restrict__ bp_packed, int nbp,
                            int* __restrict__ num_pos, double* __restrict__ sum_pos_ce,
                            int B, double* __restrict__ accum) {
    int i = blockIdx.x * blockDim.x + threadIdx.x;
    if (i < nbp) bp_packed[i] = 0ull;
    if (i < B) { num_pos[i] = 0; sum_pos_ce[i] = 0.0; }
    if (i < 2) accum[i] = 0.0;
}

// ---------------- kernel 1: matching (IoU, per-prior argmax, per-truth argmax) ----------------
__global__ __launch_bounds__(256)
void match_kernel(const float* __restrict__ priors,
                  const float* __restrict__ targets,
                  float* __restrict__ bto,
                  unsigned char* __restrict__ bti,
                  unsigned long long* __restrict__ bp_packed,
                  int P, int NOBJ) {
    int b = blockIdx.y;
    int p = blockIdx.x * blockDim.x + threadIdx.x;
    __shared__ float tx1[MAXOBJ], ty1[MAXOBJ], tx2[MAXOBJ], ty2[MAXOBJ], ta[MAXOBJ];
    __shared__ unsigned long long smax[MAXOBJ];
    if (threadIdx.x < (unsigned)NOBJ) {
        const float* t = targets + ((size_t)b * NOBJ + threadIdx.x) * 5;
        float x1 = t[0], y1 = t[1], x2 = t[2], y2 = t[3];
        tx1[threadIdx.x] = x1; ty1[threadIdx.x] = y1;
        tx2[threadIdx.x] = x2; ty2[threadIdx.x] = y2;
        ta[threadIdx.x] = (x2 - x1) * (y2 - y1);
        smax[threadIdx.x] = 0ull;
    }
    __syncthreads();
    if (p < P) {
        const float* pr = priors + (size_t)p * 4;
        float cx = pr[0], cy = pr[1], w = pr[2], h = pr[3];
        float px1 = cx - w * 0.5f, py1 = cy - h * 0.5f;
        float px2 = cx + w * 0.5f, py2 = cy + h * 0.5f;
        float pa = (px2 - px1) * (py2 - py1);
        float best = -1.0f; int bidx = 0;
        for (int t = 0; t < NOBJ; ++t) {
            float lx = fmaxf(tx1[t], px1), ly = fmaxf(ty1[t], py1);
            float rx = fminf(tx2[t], px2), ry = fminf(ty2[t], py2);
            float iw = fmaxf(rx - lx, 0.0f), ih = fmaxf(ry - ly, 0.0f);
            float inter = iw * ih;
            float iou = inter / ((ta[t] + pa) - inter + 1e-10f);
            if (iou > best) { best = iou; bidx = t; }   // strict > : first-index tie like jnp.argmax
            unsigned long long pk =
                ((unsigned long long)__float_as_uint(iou) << 32) |
                (unsigned long long)(0xFFFFFFFFu - (unsigned)p);  // inverted idx: max picks smallest p on ties
            atomicMax(&smax[t], pk);
        }
        bto[(size_t)b * P + p] = best;
        bti[(size_t)b * P + p] = (unsigned char)bidx;
    }
    __syncthreads();
    if (threadIdx.x < (unsigned)NOBJ) {
        atomicMax(&bp_packed[(size_t)b * NOBJ + threadIdx.x], smax[threadIdx.x]);
    }
}

// ---------------- kernel 2: force-assign best prior per truth (sequential, last-wins) ----------------
__global__ void force_kernel(const unsigned long long* __restrict__ bp_packed,
                             float* __restrict__ bto, unsigned char* __restrict__ bti,
                             int P, int NOBJ, int B) {
    int b = blockIdx.x * blockDim.x + threadIdx.x;
    if (b >= B) return;
    for (int j = 0; j < NOBJ; ++j) {
        unsigned long long pk = bp_packed[(size_t)b * NOBJ + j];
        unsigned p = 0xFFFFFFFFu - (unsigned)(pk & 0xFFFFFFFFull);
        bto[(size_t)b * P + p] = 2.0f;
        bti[(size_t)b * P + p] = (unsigned char)j;
    }
}

// ---------------- kernel 3: per-row logsumexp, ce, smooth-L1 (the heavy one) ----------------
__global__ __launch_bounds__(256)
void ce_kernel(const float* __restrict__ loc,
               const float* __restrict__ conf,
               const float* __restrict__ priors,
               const float* __restrict__ targets,
               const float* __restrict__ bto,
               const unsigned char* __restrict__ bti,
               float* __restrict__ ce_mine,
               int* __restrict__ num_pos,
               double* __restrict__ sum_pos_ce,
               double* __restrict__ accum,   // [0] = loss_l sum
               int P, int C, int NOBJ) {
    int lane = threadIdx.x & 63;
    int wid = threadIdx.x >> 6;
    int p = blockIdx.x * 4 + wid;
    int b = blockIdx.y;
    if (p >= P) return;
    size_t row = (size_t)b * P + p;
    const float* base = conf + row * (size_t)C;

    float m = -INFINITY;
    for (int i = lane; i < C; i += 64) m = fmaxf(m, base[i]);
    for (int o = 32; o > 0; o >>= 1) m = fmaxf(m, __shfl_xor(m, o, 64));
    float s = 0.0f;
    for (int i = lane; i < C; i += 64) s += expf(base[i] - m);
    for (int o = 32; o > 0; o >>= 1) s += __shfl_xor(s, o, 64);

    if (lane == 0) {
        float lse = m + logf(s);
        float ov = bto[row];
        int ti = bti[row];
        const float* tb = targets + ((size_t)b * NOBJ + ti) * 5;
        int cls = 0;
        if (ov >= THRESH_F) cls = (int)(tb[4] + 1.0f);
        float ce = lse - base[cls];
        bool pos = cls > 0;
        ce_mine[row] = pos ? 0.0f : ce;
        if (pos) {
            atomicAdd(&num_pos[b], 1);
            atomicAdd(&sum_pos_ce[b], (double)ce);
            const float* pr = priors + (size_t)p * 4;
            float pcx = pr[0], pcy = pr[1], pw = pr[2], ph = pr[3];
            float m0 = tb[0], m1 = tb[1], m2 = tb[2], m3 = tb[3];
            float g0 = ((m0 + m2) * 0.5f - pcx) / (VAR0_F * pw);
            float g1 = ((m1 + m3) * 0.5f - pcy) / (VAR0_F * ph);
            float g2 = logf((m2 - m0) / pw + 1e-10f) / VAR1_F;
            float g3 = logf((m3 - m1) / ph + 1e-10f) / VAR1_F;
            float g[4] = {g0, g1, g2, g3};
            const float* lrow = loc + row * 4;
            float acc = 0.0f;
            for (int d = 0; d < 4; ++d) {
                float diff = fabsf(lrow[d] - g[d]);
                acc += (diff < 1.0f) ? 0.5f * diff * diff : diff - 0.5f;
            }
            atomicAdd(&accum[0], (double)acc);
        }
    }
}

// ---------------- kernel 4: per-batch radix-select kth largest of ce_mine + loss_c partial ----------------
__global__ __launch_bounds__(256)
void select_kernel(const float* __restrict__ ce_mine,
                   const int* __restrict__ num_pos,
                   const double* __restrict__ sum_pos_ce,
                   double* __restrict__ accum,   // [1] = loss_c sum
                   int P) {
    int b = blockIdx.x;
    const float* vals = ce_mine + (size_t)b * P;
    int np = num_pos[b];
    long long k = (long long)NEG_POS_K * np;
    if (k > P - 1) k = P - 1;
    double contrib_base = sum_pos_ce[b];

    __shared__ unsigned int hist[256];
    __shared__ unsigned int s_prefix;
    __shared__ int s_krem;
    __shared__ double red[256];

    if (k <= 0) {
        if (threadIdx.x == 0) atomicAdd(&accum[1], contrib_base);
        return;
    }

    unsigned prefix = 0;
    int krem = (int)k;
    for (int pass = 0; pass < 4; ++pass) {
        int shift = 24 - 8 * pass;
        unsigned mask_hi = (pass == 0) ? 0u : (0xFFFFFFFFu << (shift + 8));
        hist[threadIdx.x] = 0;
        __syncthreads();
        for (int i = threadIdx.x; i < P; i += blockDim.x) {
            unsigned key = __float_as_uint(vals[i]);   // ce_mine >= 0 -> bits order-monotone
            if ((key & mask_hi) == prefix)
                atomicAdd(&hist[(key >> shift) & 255], 1u);
        }
        __syncthreads();
        if (threadIdx.x == 0) {
            int kr = krem;
            int d = 255;
            for (;;) {
                int c = (int)hist[d];
                if (c >= kr || d == 0) break;
                kr -= c;
                --d;
            }
            s_prefix = prefix | ((unsigned)d << shift);
            s_krem = kr;
        }
        __syncthreads();
        prefix = s_prefix;
        krem = s_krem;
        __syncthreads();
    }

    // threshold value = prefix bits; need = krem elements equal to threshold get selected.
    unsigned tbits = prefix;
    double mysum = 0.0;
    for (int i = threadIdx.x; i < P; i += blockDim.x) {
        unsigned key = __float_as_uint(vals[i]);
        if (key > tbits) mysum += (double)vals[i];
    }
    red[threadIdx.x] = mysum;
    __syncthreads();
    for (int o = blockDim.x / 2; o > 0; o >>= 1) {
        if ((int)threadIdx.x < o) red[threadIdx.x] += red[threadIdx.x + o];
        __syncthreads();
    }
    if (threadIdx.x == 0) {
        double contrib = contrib_base + red[0] + (double)krem * (double)__uint_as_float(tbits);
        atomicAdd(&accum[1], contrib);
    }
}

// ---------------- kernel 5: finalize ----------------
__global__ void finalize_kernel(const int* __restrict__ num_pos,
                                const double* __restrict__ accum,
                                float* __restrict__ out, int B) {
    if (threadIdx.x == 0 && blockIdx.x == 0) {
        long long total = 0;
        for (int b = 0; b < B; ++b) total += num_pos[b];
        double N = (double)(total > 0 ? total : 1);
        out[0] = (float)(accum[0] / N);
        out[1] = (float)(accum[1] / N);
    }
}

extern "C" void kernel_launch(void* const* d_in, const int* in_sizes, int n_in,
                              void* d_out, int out_size, void* d_ws, size_t ws_size,
                              hipStream_t stream) {
    const float* loc     = (const float*)d_in[0];
    const float* conf    = (const float*)d_in[1];
    const float* priors  = (const float*)d_in[2];
    const float* targets = (const float*)d_in[3];

    int P = in_sizes[2] / 4;
    long long nloc = in_sizes[0];
    int B = (int)(nloc / ((long long)P * 4));
    int C = (int)((long long)in_sizes[1] / ((long long)B * P));
    int NOBJ = in_sizes[3] / (B * 5);

    size_t BP = (size_t)B * P;
    auto align256 = [](size_t x) { return (x + 255) & ~(size_t)255; };
    size_t off = 0;
    float* bto = (float*)((char*)d_ws + off);              off = align256(off + BP * 4);
    unsigned char* bti = (unsigned char*)((char*)d_ws + off); off = align256(off + BP);
    float* ce_mine = (float*)((char*)d_ws + off);          off = align256(off + BP * 4);
    unsigned long long* bp_packed = (unsigned long long*)((char*)d_ws + off); off = align256(off + (size_t)B * NOBJ * 8);
    int* num_pos = (int*)((char*)d_ws + off);              off = align256(off + (size_t)B * 4);
    double* sum_pos_ce = (double*)((char*)d_ws + off);     off = align256(off + (size_t)B * 8);
    double* accum = (double*)((char*)d_ws + off);          off = align256(off + 2 * 8);

    float* out = (float*)d_out;

    int nbp = B * NOBJ;
    int ninit = nbp > B ? nbp : B;
    if (ninit < 2) ninit = 2;
    init_kernel<<<(ninit + 255) / 256, 256, 0, stream>>>(bp_packed, nbp, num_pos, sum_pos_ce, B, accum);

    dim3 mgrid((P + 255) / 256, B);
    match_kernel<<<mgrid, 256, 0, stream>>>(priors, targets, bto, bti, bp_packed, P, NOBJ);

    force_kernel<<<(B + 63) / 64, 64, 0, stream>>>(bp_packed, bto, bti, P, NOBJ, B);

    dim3 cgrid((P + 3) / 4, B);
    ce_kernel<<<cgrid, 256, 0, stream>>>(loc, conf, priors, targets, bto, bti,
                                         ce_mine, num_pos, sum_pos_ce, accum, P, C, NOBJ);

    select_kernel<<<B, 256, 0, stream>>>(ce_mine, num_pos, sum_pos_ce, accum, P);

    finalize_kernel<<<1, 1, 0, stream>>>(num_pos, accum, out, B);
}

// Round 2
// 1500.308 us; speedup vs baseline: 1.0679x; 1.0679x over previous
//
#include <hip/hip_runtime.h>
#include <cstdint>
#include <cstddef>

#define THRESH_F 0.5f
#define VAR0_F 0.1f
#define VAR1_F 0.2f
#define NEG_POS_K 3
#define MAXOBJ 64

// ---------------- init ----------------
__global__ void init_kernel(unsigned long long* __restrict__ bp_packed, int nbp,
                            int* __restrict__ num_pos, double* __restrict__ sum_pos_ce,
                            int B, double* __restrict__ accum) {
    int i = blockIdx.x * blockDim.x + threadIdx.x;
    if (i < nbp) bp_packed[i] = 0ull;
    if (i < B) { num_pos[i] = 0; sum_pos_ce[i] = 0.0; }
    if (i < 2) accum[i] = 0.0;
}

// ---------------- kernel 1: matching (IoU, per-prior argmax, per-truth argmax) ----------------
__global__ __launch_bounds__(256)
void match_kernel(const float* __restrict__ priors,
                  const float* __restrict__ targets,
                  float* __restrict__ bto,
                  unsigned char* __restrict__ bti,
                  unsigned long long* __restrict__ bp_packed,
                  int P, int NOBJ) {
    int b = blockIdx.y;
    int p = blockIdx.x * blockDim.x + threadIdx.x;
    __shared__ float tx1[MAXOBJ], ty1[MAXOBJ], tx2[MAXOBJ], ty2[MAXOBJ], ta[MAXOBJ];
    __shared__ unsigned long long smax[MAXOBJ];
    if (threadIdx.x < (unsigned)NOBJ) {
        const float* t = targets + ((size_t)b * NOBJ + threadIdx.x) * 5;
        float x1 = t[0], y1 = t[1], x2 = t[2], y2 = t[3];
        tx1[threadIdx.x] = x1; ty1[threadIdx.x] = y1;
        tx2[threadIdx.x] = x2; ty2[threadIdx.x] = y2;
        ta[threadIdx.x] = (x2 - x1) * (y2 - y1);
        smax[threadIdx.x] = 0ull;
    }
    __syncthreads();
    if (p < P) {
        const float4 prv = *(const float4*)(priors + (size_t)p * 4);
        float cx = prv.x, cy = prv.y, w = prv.z, h = prv.w;
        float px1 = cx - w * 0.5f, py1 = cy - h * 0.5f;
        float px2 = cx + w * 0.5f, py2 = cy + h * 0.5f;
        float pa = (px2 - px1) * (py2 - py1);
        float best = -1.0f; int bidx = 0;
        for (int t = 0; t < NOBJ; ++t) {
            float lx = fmaxf(tx1[t], px1), ly = fmaxf(ty1[t], py1);
            float rx = fminf(tx2[t], px2), ry = fminf(ty2[t], py2);
            float iw = fmaxf(rx - lx, 0.0f), ih = fmaxf(ry - ly, 0.0f);
            float inter = iw * ih;
            float iou = inter / ((ta[t] + pa) - inter + 1e-10f);
            if (iou > best) { best = iou; bidx = t; }   // strict > : first-index tie like jnp.argmax
            unsigned long long pk =
                ((unsigned long long)__float_as_uint(iou) << 32) |
                (unsigned long long)(0xFFFFFFFFu - (unsigned)p);  // inverted idx: max picks smallest p on ties
            if (pk > smax[t]) atomicMax(&smax[t], pk);  // stale-read skip is safe: value only grows
        }
        bto[(size_t)b * P + p] = best;
        bti[(size_t)b * P + p] = (unsigned char)bidx;
    }
    __syncthreads();
    if (threadIdx.x < (unsigned)NOBJ) {
        unsigned long long v = smax[threadIdx.x];
        unsigned long long* dst = &bp_packed[(size_t)b * NOBJ + threadIdx.x];
        if (v > *dst) atomicMax(dst, v);
    }
}

// ---------------- kernel 2: force-assign best prior per truth (sequential, last-wins) ----------------
__global__ void force_kernel(const unsigned long long* __restrict__ bp_packed,
                             float* __restrict__ bto, unsigned char* __restrict__ bti,
                             int P, int NOBJ, int B) {
    int b = blockIdx.x * blockDim.x + threadIdx.x;
    if (b >= B) return;
    for (int j = 0; j < NOBJ; ++j) {
        unsigned long long pk = bp_packed[(size_t)b * NOBJ + j];
        unsigned p = 0xFFFFFFFFu - (unsigned)(pk & 0xFFFFFFFFull);
        bto[(size_t)b * P + p] = 2.0f;
        bti[(size_t)b * P + p] = (unsigned char)j;
    }
}

// ---------------- kernel 3: per-row logsumexp, ce, smooth-L1 (the heavy one) ----------------
// 16 lanes per row; 4 rows per wave; 16 rows per 256-thread block.
__global__ __launch_bounds__(256)
void ce_kernel(const float* __restrict__ loc,
               const float* __restrict__ conf,
               const float* __restrict__ priors,
               const float* __restrict__ targets,
               const float* __restrict__ bto,
               const unsigned char* __restrict__ bti,
               float* __restrict__ ce_mine,
               int* __restrict__ num_pos,
               double* __restrict__ sum_pos_ce,
               double* __restrict__ accum,   // [0] = loss_l sum
               int P, int C, int NOBJ) {
    int lane = threadIdx.x & 63;
    int wid = threadIdx.x >> 6;
    int q = lane >> 4;           // quarter-wave id 0..3
    int lq = lane & 15;          // lane within quarter
    int p = blockIdx.x * 16 + wid * 4 + q;
    int b = blockIdx.y;
    if (p >= P) return;          // whole 16-lane quarter exits together
    size_t row = (size_t)b * P + p;
    const float* base = conf + row * (size_t)C;   // C = 81

    float v[6];
    #pragma unroll
    for (int i = 0; i < 6; ++i) {
        int j = lq + 16 * i;
        v[i] = (j < 81) ? base[j] : -INFINITY;
    }
    float m = fmaxf(fmaxf(fmaxf(v[0], v[1]), fmaxf(v[2], v[3])), fmaxf(v[4], v[5]));
    #pragma unroll
    for (int o = 8; o > 0; o >>= 1) m = fmaxf(m, __shfl_xor(m, o, 64));
    float s = 0.0f;
    #pragma unroll
    for (int i = 0; i < 6; ++i) {
        int j = lq + 16 * i;
        if (j < 81) s += __expf(v[i] - m);
    }
    #pragma unroll
    for (int o = 8; o > 0; o >>= 1) s += __shfl_xor(s, o, 64);

    if (lq == 0) {
        float lse = m + __logf(s);
        float ov = bto[row];
        int ti = bti[row];
        const float* tb = targets + ((size_t)b * NOBJ + ti) * 5;
        int cls = 0;
        if (ov >= THRESH_F) cls = (int)(tb[4] + 1.0f);
        float ce = lse - base[cls];
        bool pos = cls > 0;
        ce_mine[row] = pos ? 0.0f : ce;
        if (pos) {
            atomicAdd(&num_pos[b], 1);
            atomicAdd(&sum_pos_ce[b], (double)ce);
            const float4 prv = *(const float4*)(priors + (size_t)p * 4);
            float pcx = prv.x, pcy = prv.y, pw = prv.z, ph = prv.w;
            float m0 = tb[0], m1 = tb[1], m2 = tb[2], m3 = tb[3];
            float g0 = ((m0 + m2) * 0.5f - pcx) / (VAR0_F * pw);
            float g1 = ((m1 + m3) * 0.5f - pcy) / (VAR0_F * ph);
            float g2 = __logf((m2 - m0) / pw + 1e-10f) / VAR1_F;
            float g3 = __logf((m3 - m1) / ph + 1e-10f) / VAR1_F;
            float g[4] = {g0, g1, g2, g3};
            const float* lrow = loc + row * 4;
            float acc = 0.0f;
            #pragma unroll
            for (int d = 0; d < 4; ++d) {
                float diff = fabsf(lrow[d] - g[d]);
                acc += (diff < 1.0f) ? 0.5f * diff * diff : diff - 0.5f;
            }
            atomicAdd(&accum[0], (double)acc);
        }
    }
}

// ---------------- kernel 4: per-batch radix-select kth largest of ce_mine + loss_c partial ----------------
__global__ __launch_bounds__(256)
void select_kernel(const float* __restrict__ ce_mine,
                   const int* __restrict__ num_pos,
                   const double* __restrict__ sum_pos_ce,
                   double* __restrict__ accum,   // [1] = loss_c sum
                   int P) {
    int b = blockIdx.x;
    const float* vals = ce_mine + (size_t)b * P;
    int np = num_pos[b];
    long long k = (long long)NEG_POS_K * np;
    if (k > P - 1) k = P - 1;
    double contrib_base = sum_pos_ce[b];

    __shared__ unsigned int hist[256];
    __shared__ unsigned int s_prefix;
    __shared__ int s_krem;
    __shared__ double red[256];

    if (k <= 0) {
        if (threadIdx.x == 0) atomicAdd(&accum[1], contrib_base);
        return;
    }

    unsigned prefix = 0;
    int krem = (int)k;
    for (int pass = 0; pass < 4; ++pass) {
        int shift = 24 - 8 * pass;
        unsigned mask_hi = (pass == 0) ? 0u : (0xFFFFFFFFu << (shift + 8));
        hist[threadIdx.x] = 0;
        __syncthreads();
        for (int i = threadIdx.x; i < P; i += blockDim.x) {
            unsigned key = __float_as_uint(vals[i]);   // ce_mine >= 0 -> bits order-monotone
            if ((key & mask_hi) == prefix)
                atomicAdd(&hist[(key >> shift) & 255], 1u);
        }
        __syncthreads();
        if (threadIdx.x == 0) {
            int kr = krem;
            int d = 255;
            for (;;) {
                int c = (int)hist[d];
                if (c >= kr || d == 0) break;
                kr -= c;
                --d;
            }
            s_prefix = prefix | ((unsigned)d << shift);
            s_krem = kr;
        }
        __syncthreads();
        prefix = s_prefix;
        krem = s_krem;
        __syncthreads();
    }

    // threshold value = prefix bits; krem elements equal to threshold get selected.
    unsigned tbits = prefix;
    double mysum = 0.0;
    for (int i = threadIdx.x; i < P; i += blockDim.x) {
        unsigned key = __float_as_uint(vals[i]);
        if (key > tbits) mysum += (double)vals[i];
    }
    red[threadIdx.x] = mysum;
    __syncthreads();
    for (int o = blockDim.x / 2; o > 0; o >>= 1) {
        if ((int)threadIdx.x < o) red[threadIdx.x] += red[threadIdx.x + o];
        __syncthreads();
    }
    if (threadIdx.x == 0) {
        double contrib = contrib_base + red[0] + (double)krem * (double)__uint_as_float(tbits);
        atomicAdd(&accum[1], contrib);
    }
}

// ---------------- kernel 5: finalize ----------------
__global__ void finalize_kernel(const int* __restrict__ num_pos,
                                const double* __restrict__ accum,
                                float* __restrict__ out, int B) {
    if (threadIdx.x == 0 && blockIdx.x == 0) {
        long long total = 0;
        for (int b = 0; b < B; ++b) total += num_pos[b];
        double N = (double)(total > 0 ? total : 1);
        out[0] = (float)(accum[0] / N);
        out[1] = (float)(accum[1] / N);
    }
}

extern "C" void kernel_launch(void* const* d_in, const int* in_sizes, int n_in,
                              void* d_out, int out_size, void* d_ws, size_t ws_size,
                              hipStream_t stream) {
    const float* loc     = (const float*)d_in[0];
    const float* conf    = (const float*)d_in[1];
    const float* priors  = (const float*)d_in[2];
    const float* targets = (const float*)d_in[3];

    int P = in_sizes[2] / 4;
    long long nloc = in_sizes[0];
    int B = (int)(nloc / ((long long)P * 4));
    int C = (int)((long long)in_sizes[1] / ((long long)B * P));
    int NOBJ = in_sizes[3] / (B * 5);

    size_t BP = (size_t)B * P;
    auto align256 = [](size_t x) { return (x + 255) & ~(size_t)255; };
    size_t off = 0;
    float* bto = (float*)((char*)d_ws + off);              off = align256(off + BP * 4);
    unsigned char* bti = (unsigned char*)((char*)d_ws + off); off = align256(off + BP);
    float* ce_mine = (float*)((char*)d_ws + off);          off = align256(off + BP * 4);
    unsigned long long* bp_packed = (unsigned long long*)((char*)d_ws + off); off = align256(off + (size_t)B * NOBJ * 8);
    int* num_pos = (int*)((char*)d_ws + off);              off = align256(off + (size_t)B * 4);
    double* sum_pos_ce = (double*)((char*)d_ws + off);     off = align256(off + (size_t)B * 8);
    double* accum = (double*)((char*)d_ws + off);          off = align256(off + 2 * 8);

    float* out = (float*)d_out;

    int nbp = B * NOBJ;
    int ninit = nbp > B ? nbp : B;
    if (ninit < 2) ninit = 2;
    init_kernel<<<(ninit + 255) / 256, 256, 0, stream>>>(bp_packed, nbp, num_pos, sum_pos_ce, B, accum);

    dim3 mgrid((P + 255) / 256, B);
    match_kernel<<<mgrid, 256, 0, stream>>>(priors, targets, bto, bti, bp_packed, P, NOBJ);

    force_kernel<<<(B + 63) / 64, 64, 0, stream>>>(bp_packed, bto, bti, P, NOBJ, B);

    dim3 cgrid((P + 15) / 16, B);
    ce_kernel<<<cgrid, 256, 0, stream>>>(loc, conf, priors, targets, bto, bti,
                                         ce_mine, num_pos, sum_pos_ce, accum, P, C, NOBJ);

    select_kernel<<<B, 256, 0, stream>>>(ce_mine, num_pos, sum_pos_ce, accum, P);

    finalize_kernel<<<1, 1, 0, stream>>>(num_pos, accum, out, B);
}

// Round 3
// 599.406 us; speedup vs baseline: 2.6731x; 2.5030x over previous
//
#include <hip/hip_runtime.h>
#include <cstdint>
#include <cstddef>

#define THRESH_F 0.5f
#define VAR0_F 0.1f
#define VAR1_F 0.2f
#define NEG_POS_K 3
#define MAXOBJ 64

// ---------------- init: zero the per-truth packed argmax slots ----------------
__global__ void init_kernel(unsigned long long* __restrict__ bp_packed, int nbp) {
    int i = blockIdx.x * blockDim.x + threadIdx.x;
    if (i < nbp) bp_packed[i] = 0ull;
}

// ---------------- kernel 1: matching (IoU, per-prior argmax, per-truth argmax) ----------------
__global__ __launch_bounds__(256)
void match_kernel(const float* __restrict__ priors,
                  const float* __restrict__ targets,
                  float* __restrict__ bto,
                  unsigned char* __restrict__ bti,
                  unsigned long long* __restrict__ bp_packed,
                  int P, int NOBJ) {
    int b = blockIdx.y;
    int p = blockIdx.x * blockDim.x + threadIdx.x;
    __shared__ float tx1[MAXOBJ], ty1[MAXOBJ], tx2[MAXOBJ], ty2[MAXOBJ], ta[MAXOBJ];
    __shared__ unsigned long long smax[MAXOBJ];
    if (threadIdx.x < (unsigned)NOBJ) {
        const float* t = targets + ((size_t)b * NOBJ + threadIdx.x) * 5;
        float x1 = t[0], y1 = t[1], x2 = t[2], y2 = t[3];
        tx1[threadIdx.x] = x1; ty1[threadIdx.x] = y1;
        tx2[threadIdx.x] = x2; ty2[threadIdx.x] = y2;
        ta[threadIdx.x] = (x2 - x1) * (y2 - y1);
        smax[threadIdx.x] = 0ull;
    }
    __syncthreads();
    if (p < P) {
        const float4 prv = *(const float4*)(priors + (size_t)p * 4);
        float cx = prv.x, cy = prv.y, w = prv.z, h = prv.w;
        float px1 = cx - w * 0.5f, py1 = cy - h * 0.5f;
        float px2 = cx + w * 0.5f, py2 = cy + h * 0.5f;
        float pa = (px2 - px1) * (py2 - py1);
        float best = -1.0f; int bidx = 0;
        for (int t = 0; t < NOBJ; ++t) {
            float lx = fmaxf(tx1[t], px1), ly = fmaxf(ty1[t], py1);
            float rx = fminf(tx2[t], px2), ry = fminf(ty2[t], py2);
            float iw = fmaxf(rx - lx, 0.0f), ih = fmaxf(ry - ly, 0.0f);
            float inter = iw * ih;
            float iou = inter / ((ta[t] + pa) - inter + 1e-10f);
            if (iou > best) { best = iou; bidx = t; }   // strict > : first-index tie like jnp.argmax
            unsigned long long pk =
                ((unsigned long long)__float_as_uint(iou) << 32) |
                (unsigned long long)(0xFFFFFFFFu - (unsigned)p);  // inverted idx: max picks smallest p on ties
            if (pk > smax[t]) atomicMax(&smax[t], pk);  // stale-read skip safe: monotone increase
        }
        bto[(size_t)b * P + p] = best;
        bti[(size_t)b * P + p] = (unsigned char)bidx;
    }
    __syncthreads();
    if (threadIdx.x < (unsigned)NOBJ) {
        unsigned long long v = smax[threadIdx.x];
        unsigned long long* dst = &bp_packed[(size_t)b * NOBJ + threadIdx.x];
        if (v > *dst) atomicMax(dst, v);   // monotone, stale-read skip safe
    }
}

// ---------------- kernel 2: force-assign best prior per truth (sequential, last-wins) ----------------
__global__ void force_kernel(const unsigned long long* __restrict__ bp_packed,
                             float* __restrict__ bto, unsigned char* __restrict__ bti,
                             int P, int NOBJ, int B) {
    int b = blockIdx.x * blockDim.x + threadIdx.x;
    if (b >= B) return;
    for (int j = 0; j < NOBJ; ++j) {
        unsigned long long pk = bp_packed[(size_t)b * NOBJ + j];
        unsigned p = 0xFFFFFFFFu - (unsigned)(pk & 0xFFFFFFFFull);
        bto[(size_t)b * P + p] = 2.0f;
        bti[(size_t)b * P + p] = (unsigned char)j;
    }
}

// ---------------- kernel 3: per-row logsumexp, ce, smooth-L1. NO GLOBAL ATOMICS. ----------------
// 16 lanes per row; 4 rows per wave; 16 rows per 256-thread block.
// Per-block partial sums (pos count, sum of pos ce, smooth-L1 sum) -> part arrays.
__global__ __launch_bounds__(256)
void ce_kernel(const float* __restrict__ loc,
               const float* __restrict__ conf,
               const float* __restrict__ priors,
               const float* __restrict__ targets,
               const float* __restrict__ bto,
               const unsigned char* __restrict__ bti,
               float* __restrict__ ce_mine,
               float* __restrict__ part_np,
               float* __restrict__ part_ce,
               float* __restrict__ part_ll,
               int P, int C, int NOBJ) {
    int lane = threadIdx.x & 63;
    int wid = threadIdx.x >> 6;
    int q = lane >> 4;           // quarter-wave id 0..3
    int lq = lane & 15;          // lane within quarter
    int p = blockIdx.x * 16 + wid * 4 + q;
    int b = blockIdx.y;
    bool active = (p < P);
    size_t row = (size_t)b * P + p;
    const float* base = conf + row * (size_t)C;   // C = 81

    float cnt = 0.0f, ces = 0.0f, lls = 0.0f;

    if (active) {
        float v[6];
        #pragma unroll
        for (int i = 0; i < 6; ++i) {
            int j = lq + 16 * i;
            v[i] = (j < 81) ? base[j] : -INFINITY;
        }
        float m = fmaxf(fmaxf(fmaxf(v[0], v[1]), fmaxf(v[2], v[3])), fmaxf(v[4], v[5]));
        #pragma unroll
        for (int o = 8; o > 0; o >>= 1) m = fmaxf(m, __shfl_xor(m, o, 64));
        float s = 0.0f;
        #pragma unroll
        for (int i = 0; i < 6; ++i) {
            int j = lq + 16 * i;
            if (j < 81) s += __expf(v[i] - m);
        }
        #pragma unroll
        for (int o = 8; o > 0; o >>= 1) s += __shfl_xor(s, o, 64);

        if (lq == 0) {
            float lse = m + __logf(s);
            float ov = bto[row];
            int ti = bti[row];
            const float* tb = targets + ((size_t)b * NOBJ + ti) * 5;
            int cls = 0;
            if (ov >= THRESH_F) cls = (int)(tb[4] + 1.0f);
            float ce = lse - base[cls];
            bool pos = cls > 0;
            ce_mine[row] = pos ? 0.0f : fmaxf(ce, 0.0f);  // clamp: keep radix keys sign-bit-free
            if (pos) {
                cnt = 1.0f;
                ces = ce;
                const float4 prv = *(const float4*)(priors + (size_t)p * 4);
                float pcx = prv.x, pcy = prv.y, pw = prv.z, ph = prv.w;
                float m0 = tb[0], m1 = tb[1], m2 = tb[2], m3 = tb[3];
                float g0 = ((m0 + m2) * 0.5f - pcx) / (VAR0_F * pw);
                float g1 = ((m1 + m3) * 0.5f - pcy) / (VAR0_F * ph);
                float g2 = __logf((m2 - m0) / pw + 1e-10f) / VAR1_F;
                float g3 = __logf((m3 - m1) / ph + 1e-10f) / VAR1_F;
                float g[4] = {g0, g1, g2, g3};
                const float4 lv = *(const float4*)(loc + row * 4);
                float l[4] = {lv.x, lv.y, lv.z, lv.w};
                float acc = 0.0f;
                #pragma unroll
                for (int d = 0; d < 4; ++d) {
                    float diff = fabsf(l[d] - g[d]);
                    acc += (diff < 1.0f) ? 0.5f * diff * diff : diff - 0.5f;
                }
                lls = acc;
            }
        }
    }

    // reduce the 4 quarter-leader lanes (0,16,32,48) of each wave, then across 4 waves
    cnt += __shfl_xor(cnt, 16, 64); cnt += __shfl_xor(cnt, 32, 64);
    ces += __shfl_xor(ces, 16, 64); ces += __shfl_xor(ces, 32, 64);
    lls += __shfl_xor(lls, 16, 64); lls += __shfl_xor(lls, 32, 64);

    __shared__ float s_np[4], s_ce[4], s_ll[4];
    if (lane == 0) { s_np[wid] = cnt; s_ce[wid] = ces; s_ll[wid] = lls; }
    __syncthreads();
    if (threadIdx.x == 0) {
        size_t idx = (size_t)b * gridDim.x + blockIdx.x;
        part_np[idx] = s_np[0] + s_np[1] + s_np[2] + s_np[3];
        part_ce[idx] = s_ce[0] + s_ce[1] + s_ce[2] + s_ce[3];
        part_ll[idx] = s_ll[0] + s_ll[1] + s_ll[2] + s_ll[3];
    }
}

// ---------------- block reduction helper (1024 threads max) ----------------
__device__ inline double blockReduceD(double v, double* sd) {
    __syncthreads();
    #pragma unroll
    for (int o = 32; o > 0; o >>= 1) v += __shfl_xor(v, o, 64);
    int wid = threadIdx.x >> 6, lane = threadIdx.x & 63;
    if (lane == 0) sd[wid] = v;
    __syncthreads();
    if (threadIdx.x == 0) {
        double t = 0.0; int nw = blockDim.x >> 6;
        for (int i = 0; i < nw; ++i) t += sd[i];
        sd[0] = t;
    }
    __syncthreads();
    return sd[0];
}

// ---------------- kernel 4: per-batch partial-reduce + radix-select kth largest ----------------
__global__ __launch_bounds__(1024)
void select_kernel(const float* __restrict__ ce_mine,
                   const float* __restrict__ part_np,
                   const float* __restrict__ part_ce,
                   const float* __restrict__ part_ll,
                   double* __restrict__ np_b,
                   double* __restrict__ lc_b,
                   double* __restrict__ ll_b,
                   int P, int NBX) {
    int b = blockIdx.x;
    int tid = threadIdx.x;
    __shared__ unsigned int hist[256];
    __shared__ unsigned int s_prefix;
    __shared__ int s_krem;
    __shared__ double sd[16];

    // 1) reduce per-block partials for this batch
    double np_f = 0.0, ce_f = 0.0, ll_f = 0.0;
    for (int i = tid; i < NBX; i += blockDim.x) {
        size_t ix = (size_t)b * NBX + i;
        np_f += (double)part_np[ix];
        ce_f += (double)part_ce[ix];
        ll_f += (double)part_ll[ix];
    }
    double np_d = blockReduceD(np_f, sd);
    double ce_sum = blockReduceD(ce_f, sd);
    double ll_sum = blockReduceD(ll_f, sd);

    int np = (int)(np_d + 0.5);
    long long k = (long long)NEG_POS_K * np;
    if (k > P - 1) k = P - 1;

    if (k <= 0) {
        if (tid == 0) { np_b[b] = (double)np; lc_b[b] = ce_sum; ll_b[b] = ll_sum; }
        return;
    }

    // 2) radix-select kth largest of ce_mine (keys are non-negative floats -> bits monotone)
    const float* vals = ce_mine + (size_t)b * P;
    unsigned prefix = 0;
    int krem = (int)k;
    for (int pass = 0; pass < 4; ++pass) {
        int shift = 24 - 8 * pass;
        unsigned mask_hi = (pass == 0) ? 0u : (0xFFFFFFFFu << (shift + 8));
        if (tid < 256) hist[tid] = 0;
        __syncthreads();
        for (int i = tid; i < P; i += blockDim.x) {
            unsigned key = __float_as_uint(vals[i]);
            if ((key & mask_hi) == prefix)
                atomicAdd(&hist[(key >> shift) & 255], 1u);
        }
        __syncthreads();
        if (tid == 0) {
            int kr = krem;
            int d = 255;
            for (;;) {
                int c = (int)hist[d];
                if (c >= kr || d == 0) break;
                kr -= c;
                --d;
            }
            s_prefix = prefix | ((unsigned)d << shift);
            s_krem = kr;
        }
        __syncthreads();
        prefix = s_prefix;
        krem = s_krem;
        __syncthreads();
    }

    // 3) sum of selected: strictly-above-threshold values + krem * threshold (exact under ties)
    unsigned tbits = prefix;
    double mysum = 0.0;
    for (int i = tid; i < P; i += blockDim.x) {
        unsigned key = __float_as_uint(vals[i]);
        if (key > tbits) mysum += (double)vals[i];
    }
    double selsum = blockReduceD(mysum, sd);
    if (tid == 0) {
        np_b[b] = (double)np;
        lc_b[b] = ce_sum + selsum + (double)krem * (double)__uint_as_float(tbits);
        ll_b[b] = ll_sum;
    }
}

// ---------------- kernel 5: finalize (one wave) ----------------
__global__ void finalize_kernel(const double* __restrict__ np_b,
                                const double* __restrict__ lc_b,
                                const double* __restrict__ ll_b,
                                float* __restrict__ out, int B) {
    int t = threadIdx.x;
    double np = 0.0, lc = 0.0, ll = 0.0;
    for (int b = t; b < B; b += 64) { np += np_b[b]; lc += lc_b[b]; ll += ll_b[b]; }
    #pragma unroll
    for (int o = 32; o > 0; o >>= 1) {
        np += __shfl_xor(np, o, 64);
        lc += __shfl_xor(lc, o, 64);
        ll += __shfl_xor(ll, o, 64);
    }
    if (t == 0) {
        double N = np > 0.0 ? np : 1.0;
        out[0] = (float)(ll / N);
        out[1] = (float)(lc / N);
    }
}

extern "C" void kernel_launch(void* const* d_in, const int* in_sizes, int n_in,
                              void* d_out, int out_size, void* d_ws, size_t ws_size,
                              hipStream_t stream) {
    const float* loc     = (const float*)d_in[0];
    const float* conf    = (const float*)d_in[1];
    const float* priors  = (const float*)d_in[2];
    const float* targets = (const float*)d_in[3];

    int P = in_sizes[2] / 4;
    long long nloc = in_sizes[0];
    int B = (int)(nloc / ((long long)P * 4));
    int C = (int)((long long)in_sizes[1] / ((long long)B * P));
    int NOBJ = in_sizes[3] / (B * 5);
    int NBX = (P + 15) / 16;

    size_t BP = (size_t)B * P;
    auto align256 = [](size_t x) { return (x + 255) & ~(size_t)255; };
    size_t off = 0;
    float* bto = (float*)((char*)d_ws + off);                 off = align256(off + BP * 4);
    unsigned char* bti = (unsigned char*)((char*)d_ws + off); off = align256(off + BP);
    float* ce_mine = (float*)((char*)d_ws + off);             off = align256(off + BP * 4);
    unsigned long long* bp_packed = (unsigned long long*)((char*)d_ws + off); off = align256(off + (size_t)B * NOBJ * 8);
    float* part_np = (float*)((char*)d_ws + off);             off = align256(off + (size_t)B * NBX * 4);
    float* part_ce = (float*)((char*)d_ws + off);             off = align256(off + (size_t)B * NBX * 4);
    float* part_ll = (float*)((char*)d_ws + off);             off = align256(off + (size_t)B * NBX * 4);
    double* np_b = (double*)((char*)d_ws + off);              off = align256(off + (size_t)B * 8);
    double* lc_b = (double*)((char*)d_ws + off);              off = align256(off + (size_t)B * 8);
    double* ll_b = (double*)((char*)d_ws + off);              off = align256(off + (size_t)B * 8);

    float* out = (float*)d_out;

    int nbp = B * NOBJ;
    init_kernel<<<(nbp + 255) / 256, 256, 0, stream>>>(bp_packed, nbp);

    dim3 mgrid((P + 255) / 256, B);
    match_kernel<<<mgrid, 256, 0, stream>>>(priors, targets, bto, bti, bp_packed, P, NOBJ);

    force_kernel<<<(B + 63) / 64, 64, 0, stream>>>(bp_packed, bto, bti, P, NOBJ, B);

    dim3 cgrid(NBX, B);
    ce_kernel<<<cgrid, 256, 0, stream>>>(loc, conf, priors, targets, bto, bti,
                                         ce_mine, part_np, part_ce, part_ll, P, C, NOBJ);

    select_kernel<<<B, 1024, 0, stream>>>(ce_mine, part_np, part_ce, part_ll,
                                          np_b, lc_b, ll_b, P, NBX);

    finalize_kernel<<<1, 64, 0, stream>>>(np_b, lc_b, ll_b, out, B);
}

// Round 4
// 328.916 us; speedup vs baseline: 4.8713x; 1.8224x over previous
//
#include <hip/hip_runtime.h>
#include <cstdint>
#include <cstddef>

#define THRESH_F 0.5f
#define VAR0_F 0.1f
#define VAR1_F 0.2f
#define NEG_POS_K 3
#define MAXOBJ 64

// ---------------- init: zero the per-truth packed argmax slots ----------------
__global__ void init_kernel(unsigned long long* __restrict__ bp_packed, int nbp) {
    int i = blockIdx.x * blockDim.x + threadIdx.x;
    if (i < nbp) bp_packed[i] = 0ull;
}

// ---------------- kernel 1: matching (IoU, per-prior argmax, per-truth argmax) ----------------
// Per-truth max is wave-butterfly-reduced (no per-lane atomics -> no CAS storm).
__global__ __launch_bounds__(256)
void match_kernel(const float* __restrict__ priors,
                  const float* __restrict__ targets,
                  float* __restrict__ bto,
                  unsigned char* __restrict__ bti,
                  unsigned long long* __restrict__ bp_packed,
                  int P, int NOBJ) {
    int b = blockIdx.y;
    int tid = threadIdx.x;
    int lane = tid & 63;
    int p = blockIdx.x * blockDim.x + tid;
    bool valid = (p < P);
    __shared__ float tx1[MAXOBJ], ty1[MAXOBJ], tx2[MAXOBJ], ty2[MAXOBJ], ta[MAXOBJ];
    __shared__ unsigned long long smax[MAXOBJ];
    if (tid < (unsigned)NOBJ) {
        const float* t = targets + ((size_t)b * NOBJ + tid) * 5;
        float x1 = t[0], y1 = t[1], x2 = t[2], y2 = t[3];
        tx1[tid] = x1; ty1[tid] = y1;
        tx2[tid] = x2; ty2[tid] = y2;
        ta[tid] = (x2 - x1) * (y2 - y1);
        smax[tid] = 0ull;
    }
    __syncthreads();

    int pc = valid ? p : (P - 1);
    const float4 prv = *(const float4*)(priors + (size_t)pc * 4);
    float cx = prv.x, cy = prv.y, w = prv.z, h = prv.w;
    float px1 = cx - w * 0.5f, py1 = cy - h * 0.5f;
    float px2 = cx + w * 0.5f, py2 = cy + h * 0.5f;
    float pa = (px2 - px1) * (py2 - py1);
    float best = -1.0f; int bidx = 0;

    for (int t = 0; t < NOBJ; ++t) {
        float lx = fmaxf(tx1[t], px1), ly = fmaxf(ty1[t], py1);
        float rx = fminf(tx2[t], px2), ry = fminf(ty2[t], py2);
        float iw = fmaxf(rx - lx, 0.0f), ih = fmaxf(ry - ly, 0.0f);
        float inter = iw * ih;
        float iou = inter / ((ta[t] + pa) - inter + 1e-10f);
        if (iou > best) { best = iou; bidx = t; }   // strict > : first-index tie like jnp.argmax
        unsigned long long pk = valid ?
            (((unsigned long long)__float_as_uint(iou) << 32) |
             (unsigned long long)(0xFFFFFFFFu - (unsigned)p)) : 0ull;  // inverted idx: max picks smallest p
        // wave-level max reduction (uniform control flow, all 64 lanes)
        #pragma unroll
        for (int o = 32; o > 0; o >>= 1) {
            unsigned long long other = __shfl_xor(pk, o, 64);
            if (other > pk) pk = other;
        }
        if (lane == 0 && pk > smax[t]) atomicMax(&smax[t], pk);  // 4 contenders/block, filtered
    }
    if (valid) {
        bto[(size_t)b * P + p] = best;
        bti[(size_t)b * P + p] = (unsigned char)bidx;
    }
    __syncthreads();
    if (tid < (unsigned)NOBJ) {
        unsigned long long v = smax[tid];
        unsigned long long* dst = &bp_packed[(size_t)b * NOBJ + tid];
        if (v > *dst) atomicMax(dst, v);   // monotone, stale-read skip safe
    }
}

// ---------------- kernel 2: force-assign best prior per truth (sequential, last-wins) ----------------
__global__ void force_kernel(const unsigned long long* __restrict__ bp_packed,
                             float* __restrict__ bto, unsigned char* __restrict__ bti,
                             int P, int NOBJ, int B) {
    int b = blockIdx.x * blockDim.x + threadIdx.x;
    if (b >= B) return;
    for (int j = 0; j < NOBJ; ++j) {
        unsigned long long pk = bp_packed[(size_t)b * NOBJ + j];
        unsigned p = 0xFFFFFFFFu - (unsigned)(pk & 0xFFFFFFFFull);
        bto[(size_t)b * P + p] = 2.0f;
        bti[(size_t)b * P + p] = (unsigned char)j;
    }
}

// ---------------- kernel 3: per-row logsumexp, ce, smooth-L1. NO GLOBAL ATOMICS. ----------------
// 16 lanes per row; 4 rows per wave; 16 rows per 256-thread block.
__global__ __launch_bounds__(256)
void ce_kernel(const float* __restrict__ loc,
               const float* __restrict__ conf,
               const float* __restrict__ priors,
               const float* __restrict__ targets,
               const float* __restrict__ bto,
               const unsigned char* __restrict__ bti,
               float* __restrict__ ce_mine,
               float* __restrict__ part_np,
               float* __restrict__ part_ce,
               float* __restrict__ part_ll,
               int P, int C, int NOBJ) {
    int lane = threadIdx.x & 63;
    int wid = threadIdx.x >> 6;
    int q = lane >> 4;           // quarter-wave id 0..3
    int lq = lane & 15;          // lane within quarter
    int p = blockIdx.x * 16 + wid * 4 + q;
    int b = blockIdx.y;
    bool active = (p < P);
    size_t row = (size_t)b * P + p;
    const float* base = conf + row * (size_t)C;   // C = 81

    float cnt = 0.0f, ces = 0.0f, lls = 0.0f;

    if (active) {
        float v[6];
        #pragma unroll
        for (int i = 0; i < 6; ++i) {
            int j = lq + 16 * i;
            v[i] = (j < 81) ? base[j] : -INFINITY;
        }
        float m = fmaxf(fmaxf(fmaxf(v[0], v[1]), fmaxf(v[2], v[3])), fmaxf(v[4], v[5]));
        #pragma unroll
        for (int o = 8; o > 0; o >>= 1) m = fmaxf(m, __shfl_xor(m, o, 64));
        float s = 0.0f;
        #pragma unroll
        for (int i = 0; i < 6; ++i) {
            int j = lq + 16 * i;
            if (j < 81) s += __expf(v[i] - m);
        }
        #pragma unroll
        for (int o = 8; o > 0; o >>= 1) s += __shfl_xor(s, o, 64);

        if (lq == 0) {
            float lse = m + __logf(s);
            float ov = bto[row];
            int ti = bti[row];
            const float* tb = targets + ((size_t)b * NOBJ + ti) * 5;
            int cls = 0;
            if (ov >= THRESH_F) cls = (int)(tb[4] + 1.0f);
            float ce = lse - base[cls];
            bool pos = cls > 0;
            ce_mine[row] = pos ? 0.0f : fmaxf(ce, 0.0f);  // clamp: keep radix keys sign-bit-free
            if (pos) {
                cnt = 1.0f;
                ces = ce;
                const float4 prv = *(const float4*)(priors + (size_t)p * 4);
                float pcx = prv.x, pcy = prv.y, pw = prv.z, ph = prv.w;
                float m0 = tb[0], m1 = tb[1], m2 = tb[2], m3 = tb[3];
                float g0 = ((m0 + m2) * 0.5f - pcx) / (VAR0_F * pw);
                float g1 = ((m1 + m3) * 0.5f - pcy) / (VAR0_F * ph);
                float g2 = __logf((m2 - m0) / pw + 1e-10f) / VAR1_F;
                float g3 = __logf((m3 - m1) / ph + 1e-10f) / VAR1_F;
                float g[4] = {g0, g1, g2, g3};
                const float4 lv = *(const float4*)(loc + row * 4);
                float l[4] = {lv.x, lv.y, lv.z, lv.w};
                float acc = 0.0f;
                #pragma unroll
                for (int d = 0; d < 4; ++d) {
                    float diff = fabsf(l[d] - g[d]);
                    acc += (diff < 1.0f) ? 0.5f * diff * diff : diff - 0.5f;
                }
                lls = acc;
            }
        }
    }

    // reduce the 4 quarter-leader lanes (0,16,32,48) of each wave, then across 4 waves
    cnt += __shfl_xor(cnt, 16, 64); cnt += __shfl_xor(cnt, 32, 64);
    ces += __shfl_xor(ces, 16, 64); ces += __shfl_xor(ces, 32, 64);
    lls += __shfl_xor(lls, 16, 64); lls += __shfl_xor(lls, 32, 64);

    __shared__ float s_np[4], s_ce[4], s_ll[4];
    if (lane == 0) { s_np[wid] = cnt; s_ce[wid] = ces; s_ll[wid] = lls; }
    __syncthreads();
    if (threadIdx.x == 0) {
        size_t idx = (size_t)b * gridDim.x + blockIdx.x;
        part_np[idx] = s_np[0] + s_np[1] + s_np[2] + s_np[3];
        part_ce[idx] = s_ce[0] + s_ce[1] + s_ce[2] + s_ce[3];
        part_ll[idx] = s_ll[0] + s_ll[1] + s_ll[2] + s_ll[3];
    }
}

// ---------------- block reduction helper (1024 threads max) ----------------
__device__ inline double blockReduceD(double v, double* sd) {
    __syncthreads();
    #pragma unroll
    for (int o = 32; o > 0; o >>= 1) v += __shfl_xor(v, o, 64);
    int wid = threadIdx.x >> 6, lane = threadIdx.x & 63;
    if (lane == 0) sd[wid] = v;
    __syncthreads();
    if (threadIdx.x == 0) {
        double t = 0.0; int nw = blockDim.x >> 6;
        for (int i = 0; i < nw; ++i) t += sd[i];
        sd[0] = t;
    }
    __syncthreads();
    return sd[0];
}

// ---------------- kernel 4: per-batch partial-reduce + radix-select kth largest ----------------
__global__ __launch_bounds__(1024)
void select_kernel(const float* __restrict__ ce_mine,
                   const float* __restrict__ part_np,
                   const float* __restrict__ part_ce,
                   const float* __restrict__ part_ll,
                   double* __restrict__ np_b,
                   double* __restrict__ lc_b,
                   double* __restrict__ ll_b,
                   int P, int NBX) {
    int b = blockIdx.x;
    int tid = threadIdx.x;
    __shared__ unsigned int hist[256];
    __shared__ unsigned int s_prefix;
    __shared__ int s_krem;
    __shared__ double sd[16];

    // 1) reduce per-block partials for this batch
    double np_f = 0.0, ce_f = 0.0, ll_f = 0.0;
    for (int i = tid; i < NBX; i += blockDim.x) {
        size_t ix = (size_t)b * NBX + i;
        np_f += (double)part_np[ix];
        ce_f += (double)part_ce[ix];
        ll_f += (double)part_ll[ix];
    }
    double np_d = blockReduceD(np_f, sd);
    double ce_sum = blockReduceD(ce_f, sd);
    double ll_sum = blockReduceD(ll_f, sd);

    int np = (int)(np_d + 0.5);
    long long k = (long long)NEG_POS_K * np;
    if (k > P - 1) k = P - 1;

    if (k <= 0) {
        if (tid == 0) { np_b[b] = (double)np; lc_b[b] = ce_sum; ll_b[b] = ll_sum; }
        return;
    }

    // 2) radix-select kth largest of ce_mine (keys are non-negative floats -> bits monotone)
    const float* vals = ce_mine + (size_t)b * P;
    unsigned prefix = 0;
    int krem = (int)k;
    for (int pass = 0; pass < 4; ++pass) {
        int shift = 24 - 8 * pass;
        unsigned mask_hi = (pass == 0) ? 0u : (0xFFFFFFFFu << (shift + 8));
        if (tid < 256) hist[tid] = 0;
        __syncthreads();
        for (int i = tid; i < P; i += blockDim.x) {
            unsigned key = __float_as_uint(vals[i]);
            if ((key & mask_hi) == prefix)
                atomicAdd(&hist[(key >> shift) & 255], 1u);
        }
        __syncthreads();
        if (tid == 0) {
            int kr = krem;
            int d = 255;
            for (;;) {
                int c = (int)hist[d];
                if (c >= kr || d == 0) break;
                kr -= c;
                --d;
            }
            s_prefix = prefix | ((unsigned)d << shift);
            s_krem = kr;
        }
        __syncthreads();
        prefix = s_prefix;
        krem = s_krem;
        __syncthreads();
    }

    // 3) sum of selected: strictly-above-threshold values + krem * threshold (exact under ties)
    unsigned tbits = prefix;
    double mysum = 0.0;
    for (int i = tid; i < P; i += blockDim.x) {
        unsigned key = __float_as_uint(vals[i]);
        if (key > tbits) mysum += (double)vals[i];
    }
    double selsum = blockReduceD(mysum, sd);
    if (tid == 0) {
        np_b[b] = (double)np;
        lc_b[b] = ce_sum + selsum + (double)krem * (double)__uint_as_float(tbits);
        ll_b[b] = ll_sum;
    }
}

// ---------------- kernel 5: finalize (one wave) ----------------
__global__ void finalize_kernel(const double* __restrict__ np_b,
                                const double* __restrict__ lc_b,
                                const double* __restrict__ ll_b,
                                float* __restrict__ out, int B) {
    int t = threadIdx.x;
    double np = 0.0, lc = 0.0, ll = 0.0;
    for (int b = t; b < B; b += 64) { np += np_b[b]; lc += lc_b[b]; ll += ll_b[b]; }
    #pragma unroll
    for (int o = 32; o > 0; o >>= 1) {
        np += __shfl_xor(np, o, 64);
        lc += __shfl_xor(lc, o, 64);
        ll += __shfl_xor(ll, o, 64);
    }
    if (t == 0) {
        double N = np > 0.0 ? np : 1.0;
        out[0] = (float)(ll / N);
        out[1] = (float)(lc / N);
    }
}

extern "C" void kernel_launch(void* const* d_in, const int* in_sizes, int n_in,
                              void* d_out, int out_size, void* d_ws, size_t ws_size,
                              hipStream_t stream) {
    const float* loc     = (const float*)d_in[0];
    const float* conf    = (const float*)d_in[1];
    const float* priors  = (const float*)d_in[2];
    const float* targets = (const float*)d_in[3];

    int P = in_sizes[2] / 4;
    long long nloc = in_sizes[0];
    int B = (int)(nloc / ((long long)P * 4));
    int C = (int)((long long)in_sizes[1] / ((long long)B * P));
    int NOBJ = in_sizes[3] / (B * 5);
    int NBX = (P + 15) / 16;

    size_t BP = (size_t)B * P;
    auto align256 = [](size_t x) { return (x + 255) & ~(size_t)255; };
    size_t off = 0;
    float* bto = (float*)((char*)d_ws + off);                 off = align256(off + BP * 4);
    unsigned char* bti = (unsigned char*)((char*)d_ws + off); off = align256(off + BP);
    float* ce_mine = (float*)((char*)d_ws + off);             off = align256(off + BP * 4);
    unsigned long long* bp_packed = (unsigned long long*)((char*)d_ws + off); off = align256(off + (size_t)B * NOBJ * 8);
    float* part_np = (float*)((char*)d_ws + off);             off = align256(off + (size_t)B * NBX * 4);
    float* part_ce = (float*)((char*)d_ws + off);             off = align256(off + (size_t)B * NBX * 4);
    float* part_ll = (float*)((char*)d_ws + off);             off = align256(off + (size_t)B * NBX * 4);
    double* np_b = (double*)((char*)d_ws + off);              off = align256(off + (size_t)B * 8);
    double* lc_b = (double*)((char*)d_ws + off);              off = align256(off + (size_t)B * 8);
    double* ll_b = (double*)((char*)d_ws + off);              off = align256(off + (size_t)B * 8);

    float* out = (float*)d_out;

    int nbp = B * NOBJ;
    init_kernel<<<(nbp + 255) / 256, 256, 0, stream>>>(bp_packed, nbp);

    dim3 mgrid((P + 255) / 256, B);
    match_kernel<<<mgrid, 256, 0, stream>>>(priors, targets, bto, bti, bp_packed, P, NOBJ);

    force_kernel<<<(B + 63) / 64, 64, 0, stream>>>(bp_packed, bto, bti, P, NOBJ, B);

    dim3 cgrid(NBX, B);
    ce_kernel<<<cgrid, 256, 0, stream>>>(loc, conf, priors, targets, bto, bti,
                                         ce_mine, part_np, part_ce, part_ll, P, C, NOBJ);

    select_kernel<<<B, 1024, 0, stream>>>(ce_mine, part_np, part_ce, part_ll,
                                          np_b, lc_b, ll_b, P, NBX);

    finalize_kernel<<<1, 64, 0, stream>>>(np_b, lc_b, ll_b, out, B);
}